// Round 1
// baseline (2061.996 us; speedup 1.0000x reference)
//
#include <hip/hip_runtime.h>

#define NN 50000
#define EE 800000
#define EP (EE + NN)   // 850000 edges incl. self loops
#define FIN0 128
#define HIDD 64
#define NH 4
#define HC 256
#define NOUT 256
#define NEG_SLOPE 0.2f
#define LN_EPS 1e-5f

// ---------------- edge index handling (int32 vs int64 hedge) ----------------
__global__ void k_detect(const int* __restrict__ raw, int* __restrict__ flag) {
    __shared__ int any;
    if (threadIdx.x == 0) any = 0;
    __syncthreads();
    int found = 0;
    for (int i = threadIdx.x; i < 4096; i += 256)
        if (raw[2 * i + 1] != 0) found = 1;
    if (found) atomicOr(&any, 1);
    __syncthreads();
    if (threadIdx.x == 0) *flag = any;   // 1 => int32 layout, 0 => int64 (low words)
}

__global__ void k_build_edges(const int* __restrict__ raw, const int* __restrict__ flag,
                              int* __restrict__ src, int* __restrict__ dst) {
    int e = blockIdx.x * blockDim.x + threadIdx.x;
    if (e >= EP) return;
    if (e >= EE) { src[e] = e - EE; dst[e] = e - EE; return; }
    if (*flag) { src[e] = raw[e];     dst[e] = raw[EE + e]; }
    else       { src[e] = raw[2 * e]; dst[e] = raw[2 * (EE + e)]; }
}

// ---------------- input projection: h0 = relu(x @ w_in + b_in) ----------------
__global__ void k_in_proj(const float* __restrict__ x, const float* __restrict__ w,
                          const float* __restrict__ b, float* __restrict__ h0) {
    __shared__ float xs[4][FIN0];
    int wave = threadIdx.x >> 6;
    int lane = threadIdx.x & 63;
    int row = blockIdx.x * 4 + wave;
    xs[wave][lane]      = x[row * FIN0 + lane];
    xs[wave][lane + 64] = x[row * FIN0 + lane + 64];
    __syncthreads();
    float acc = b[lane];
    #pragma unroll 8
    for (int k = 0; k < FIN0; ++k)
        acc += xs[wave][k] * w[k * HIDD + lane];
    h0[row * HIDD + lane] = fmaxf(acc, 0.f);
}

// -------- GAT linear + attention dots: hp = h @ lw; a_s/a_d per head --------
template<int FIN>
__global__ void k_lin_att(const float* __restrict__ h, const float* __restrict__ lw,
                          const float* __restrict__ att_s, const float* __restrict__ att_d,
                          float* __restrict__ hp, float* __restrict__ as_, float* __restrict__ ad_) {
    const int RPB = 8;
    __shared__ float hs[RPB][FIN];
    int j = threadIdx.x;            // output column 0..255
    int base = blockIdx.x * RPB;
    for (int idx = j; idx < RPB * FIN; idx += 256) {
        int r = idx / FIN, k = idx % FIN;
        hs[r][k] = h[(base + r) * FIN + k];
    }
    __syncthreads();
    float acc[RPB];
    #pragma unroll
    for (int r = 0; r < RPB; ++r) acc[r] = 0.f;
    for (int k = 0; k < FIN; ++k) {
        float w = lw[k * HC + j];
        #pragma unroll
        for (int r = 0; r < RPB; ++r) acc[r] += hs[r][k] * w;
    }
    float asv = att_s[j], adv = att_d[j];
    int head = j >> 6;              // wave == head (256 threads)
    #pragma unroll
    for (int r = 0; r < RPB; ++r) {
        hp[(size_t)(base + r) * HC + j] = acc[r];
        float ps = acc[r] * asv;
        float pd = acc[r] * adv;
        #pragma unroll
        for (int o = 32; o >= 1; o >>= 1) {
            ps += __shfl_xor(ps, o, 64);
            pd += __shfl_xor(pd, o, 64);
        }
        if ((j & 63) == 0) {
            as_[(base + r) * NH + head] = ps;
            ad_[(base + r) * NH + head] = pd;
        }
    }
}

// ---------------- softmax denominator: z[dst,h] += exp(e) ----------------
__global__ void k_edge_z(const int* __restrict__ src, const int* __restrict__ dst,
                         const float* __restrict__ as_, const float* __restrict__ ad_,
                         float* __restrict__ z) {
    int e = blockIdx.x * blockDim.x + threadIdx.x;
    if (e >= EP) return;
    int s = src[e], d = dst[e];
    #pragma unroll
    for (int h = 0; h < NH; ++h) {
        float ev = as_[s * NH + h] + ad_[d * NH + h];
        ev = ev > 0.f ? ev : ev * NEG_SLOPE;
        atomicAdd(&z[d * NH + h], expf(ev));
    }
}

// -------- aggregation: agg[dst] += alpha * hp[src]  (one wave per edge) --------
__global__ void k_edge_agg(const int* __restrict__ src, const int* __restrict__ dst,
                           const float* __restrict__ hp,
                           const float* __restrict__ as_, const float* __restrict__ ad_,
                           const float* __restrict__ z, float* __restrict__ agg) {
    int e = (blockIdx.x * blockDim.x + threadIdx.x) >> 6;
    int lane = threadIdx.x & 63;
    if (e >= EP) return;
    int s = src[e], d = dst[e];
    float alpha[NH];
    #pragma unroll
    for (int h = 0; h < NH; ++h) {
        float ev = as_[s * NH + h] + ad_[d * NH + h];
        ev = ev > 0.f ? ev : ev * NEG_SLOPE;
        alpha[h] = expf(ev) / (z[d * NH + h] + 1e-16f);
    }
    #pragma unroll
    for (int h = 0; h < NH; ++h) {
        int c = h * 64 + lane;
        atomicAdd(&agg[(size_t)d * HC + c], alpha[h] * hp[(size_t)s * HC + c]);
    }
}

// ---------------- bias + layernorm + relu (in place), wave per node ----------------
__global__ void k_ln_relu(float* __restrict__ v, const float* __restrict__ bias,
                          const float* __restrict__ g, const float* __restrict__ b) {
    int wave = threadIdx.x >> 6, lane = threadIdx.x & 63;
    int n = blockIdx.x * 4 + wave;
    size_t o = (size_t)n * HC + lane;
    float x0 = v[o]       + bias[lane];
    float x1 = v[o + 64]  + bias[lane + 64];
    float x2 = v[o + 128] + bias[lane + 128];
    float x3 = v[o + 192] + bias[lane + 192];
    float sum = x0 + x1 + x2 + x3;
    #pragma unroll
    for (int off = 32; off >= 1; off >>= 1) sum += __shfl_xor(sum, off, 64);
    float mu = sum * (1.f / HC);
    float d0 = x0 - mu, d1 = x1 - mu, d2 = x2 - mu, d3 = x3 - mu;
    float vs = d0 * d0 + d1 * d1 + d2 * d2 + d3 * d3;
    #pragma unroll
    for (int off = 32; off >= 1; off >>= 1) vs += __shfl_xor(vs, off, 64);
    float rs = rsqrtf(vs * (1.f / HC) + LN_EPS);
    v[o]       = fmaxf(d0 * rs * g[lane]       + b[lane], 0.f);
    v[o + 64]  = fmaxf(d1 * rs * g[lane + 64]  + b[lane + 64], 0.f);
    v[o + 128] = fmaxf(d2 * rs * g[lane + 128] + b[lane + 128], 0.f);
    v[o + 192] = fmaxf(d3 * rs * g[lane + 192] + b[lane + 192], 0.f);
}

// ---------------- mean pool (column sums) ----------------
__global__ void k_colsum(const float* __restrict__ v, float* __restrict__ gacc) {
    int j = threadIdx.x;
    float s = 0.f;
    for (int n = blockIdx.x; n < NN; n += gridDim.x)
        s += v[(size_t)n * HC + j];
    atomicAdd(&gacc[j], s);
}

// ---------------- final GEMV: out = (g/N) @ w_out + b_out ----------------
__global__ void k_final(const float* __restrict__ gacc, const float* __restrict__ w,
                        const float* __restrict__ b, float* __restrict__ out) {
    int o = threadIdx.x;
    float acc = b[o];
    for (int k = 0; k < HC; ++k)
        acc += (gacc[k] * (1.f / NN)) * w[k * NOUT + o];
    out[o] = acc;
}

extern "C" void kernel_launch(void* const* d_in, const int* in_sizes, int n_in,
                              void* d_out, int out_size, void* d_ws, size_t ws_size,
                              hipStream_t stream) {
    const float* x      = (const float*)d_in[0];
    const int*   eiraw  = (const int*)d_in[1];
    const float* w_in   = (const float*)d_in[2];
    const float* b_in   = (const float*)d_in[3];
    const float* lin0_w = (const float*)d_in[4];
    const float* atts0  = (const float*)d_in[5];
    const float* attd0  = (const float*)d_in[6];
    const float* bias0  = (const float*)d_in[7];
    const float* ln0g   = (const float*)d_in[8];
    const float* ln0b   = (const float*)d_in[9];
    const float* lin1_w = (const float*)d_in[10];
    const float* atts1  = (const float*)d_in[11];
    const float* attd1  = (const float*)d_in[12];
    const float* bias1  = (const float*)d_in[13];
    const float* ln1g   = (const float*)d_in[14];
    const float* ln1b   = (const float*)d_in[15];
    const float* w_out  = (const float*)d_in[16];
    const float* b_out  = (const float*)d_in[17];
    float* out = (float*)d_out;

    char* ws = (char*)d_ws;
    size_t off = 0;
    auto alloc = [&](size_t bytes) {
        void* p = ws + off;
        off = (off + bytes + 255) & ~(size_t)255;
        return p;
    };
    int*   src  = (int*)  alloc((size_t)EP * 4);
    int*   dst  = (int*)  alloc((size_t)EP * 4);
    int*   flag = (int*)  alloc(256);
    float* h0   = (float*)alloc((size_t)NN * HIDD * 4);
    float* hp   = (float*)alloc((size_t)NN * HC * 4);
    float* agg  = (float*)alloc((size_t)NN * HC * 4);
    float* as_  = (float*)alloc((size_t)NN * NH * 4);
    float* ad_  = (float*)alloc((size_t)NN * NH * 4);
    float* z    = (float*)alloc((size_t)NN * NH * 4);
    float* gacc = (float*)alloc(HC * 4);

    k_detect<<<1, 256, 0, stream>>>(eiraw, flag);
    k_build_edges<<<(EP + 255) / 256, 256, 0, stream>>>(eiraw, flag, src, dst);

    // input projection
    k_in_proj<<<NN / 4, 256, 0, stream>>>(x, w_in, b_in, h0);

    // ---- GAT layer 0 ----
    k_lin_att<HIDD><<<NN / 8, 256, 0, stream>>>(h0, lin0_w, atts0, attd0, hp, as_, ad_);
    hipMemsetAsync(z, 0, (size_t)NN * NH * 4, stream);
    k_edge_z<<<(EP + 255) / 256, 256, 0, stream>>>(src, dst, as_, ad_, z);
    hipMemsetAsync(agg, 0, (size_t)NN * HC * 4, stream);
    k_edge_agg<<<EP / 4, 256, 0, stream>>>(src, dst, hp, as_, ad_, z, agg);
    k_ln_relu<<<NN / 4, 256, 0, stream>>>(agg, bias0, ln0g, ln0b);

    // ---- GAT layer 1 ----
    k_lin_att<HC><<<NN / 8, 256, 0, stream>>>(agg, lin1_w, atts1, attd1, hp, as_, ad_);
    hipMemsetAsync(z, 0, (size_t)NN * NH * 4, stream);
    k_edge_z<<<(EP + 255) / 256, 256, 0, stream>>>(src, dst, as_, ad_, z);
    hipMemsetAsync(agg, 0, (size_t)NN * HC * 4, stream);
    k_edge_agg<<<EP / 4, 256, 0, stream>>>(src, dst, hp, as_, ad_, z, agg);
    k_ln_relu<<<NN / 4, 256, 0, stream>>>(agg, bias1, ln1g, ln1b);

    // ---- pool + output ----
    hipMemsetAsync(gacc, 0, HC * 4, stream);
    k_colsum<<<512, 256, 0, stream>>>(agg, gacc);
    k_final<<<1, 256, 0, stream>>>(gacc, w_out, b_out, out);
}

// Round 2
// 725.407 us; speedup vs baseline: 2.8425x; 2.8425x over previous
//
#include <hip/hip_runtime.h>

#define NN 50000
#define EE 800000
#define EP (EE + NN)   // 850000 edges incl. self loops
#define FIN0 128
#define HIDD 64
#define NH 4
#define HC 256
#define NOUT 256
#define NEG_SLOPE 0.2f
#define LN_EPS 1e-5f

// ---------------- edge index handling (int32 vs int64 hedge) ----------------
__global__ void k_detect(const int* __restrict__ raw, int* __restrict__ flag) {
    __shared__ int any;
    if (threadIdx.x == 0) any = 0;
    __syncthreads();
    int found = 0;
    for (int i = threadIdx.x; i < 4096; i += 256)
        if (raw[2 * i + 1] != 0) found = 1;
    if (found) atomicOr(&any, 1);
    __syncthreads();
    if (threadIdx.x == 0) *flag = any;   // 1 => int32 layout, 0 => int64 (low words)
}

__global__ void k_build_edges(const int* __restrict__ raw, const int* __restrict__ flag,
                              int* __restrict__ src, int* __restrict__ dst) {
    int e = blockIdx.x * blockDim.x + threadIdx.x;
    if (e >= EP) return;
    if (e >= EE) { src[e] = e - EE; dst[e] = e - EE; return; }
    if (*flag) { src[e] = raw[e];     dst[e] = raw[EE + e]; }
    else       { src[e] = raw[2 * e]; dst[e] = raw[2 * (EE + e)]; }
}

// ---------------- CSR build ----------------
__global__ void k_hist(const int* __restrict__ dst, int* __restrict__ deg) {
    int e = blockIdx.x * blockDim.x + threadIdx.x;
    if (e < EP) atomicAdd(&deg[dst[e]], 1);
}

// single block, 1024 threads: exclusive scan deg -> rowptr (NN+1)
__global__ void k_scan(const int* __restrict__ deg, int* __restrict__ rowptr) {
    __shared__ int wsum[16];
    __shared__ int carry_s;
    int lane = threadIdx.x & 63, wid = threadIdx.x >> 6;
    if (threadIdx.x == 0) { carry_s = 0; rowptr[0] = 0; }
    __syncthreads();
    for (int base = 0; base < NN; base += 1024) {
        int i = base + threadIdx.x;
        int x = (i < NN) ? deg[i] : 0;
        #pragma unroll
        for (int o = 1; o < 64; o <<= 1) {
            int t = __shfl_up(x, o, 64);
            if (lane >= o) x += t;
        }
        if (lane == 63) wsum[wid] = x;
        __syncthreads();
        if (wid == 0 && lane < 16) {
            int s = wsum[lane];
            #pragma unroll
            for (int o = 1; o < 16; o <<= 1) {
                int t = __shfl_up(s, o, 64);
                if (lane >= o) s += t;
            }
            wsum[lane] = s;
        }
        __syncthreads();
        int offset = carry_s + (wid > 0 ? wsum[wid - 1] : 0);
        if (i < NN) rowptr[i + 1] = offset + x;
        __syncthreads();
        if (threadIdx.x == 0) carry_s += wsum[15];
        __syncthreads();
    }
}

__global__ void k_copy(const int* __restrict__ a, int* __restrict__ b, int n) {
    int i = blockIdx.x * blockDim.x + threadIdx.x;
    if (i < n) b[i] = a[i];
}

__global__ void k_scatter(const int* __restrict__ src, const int* __restrict__ dst,
                          int* __restrict__ cursor, int* __restrict__ esrc) {
    int e = blockIdx.x * blockDim.x + threadIdx.x;
    if (e >= EP) return;
    int pos = atomicAdd(&cursor[dst[e]], 1);
    esrc[pos] = src[e];
}

// ---------------- input projection: h0 = relu(x @ w_in + b_in) ----------------
__global__ void k_in_proj(const float* __restrict__ x, const float* __restrict__ w,
                          const float* __restrict__ b, float* __restrict__ h0) {
    __shared__ float xs[4][FIN0];
    int wave = threadIdx.x >> 6;
    int lane = threadIdx.x & 63;
    int row = blockIdx.x * 4 + wave;
    xs[wave][lane]      = x[row * FIN0 + lane];
    xs[wave][lane + 64] = x[row * FIN0 + lane + 64];
    __syncthreads();
    float acc = b[lane];
    #pragma unroll 8
    for (int k = 0; k < FIN0; ++k)
        acc += xs[wave][k] * w[k * HIDD + lane];
    h0[row * HIDD + lane] = fmaxf(acc, 0.f);
}

// -------- GAT linear + attention dots: hp = h @ lw; a_s/a_d per head --------
template<int FIN>
__global__ void k_lin_att(const float* __restrict__ h, const float* __restrict__ lw,
                          const float* __restrict__ att_s, const float* __restrict__ att_d,
                          float* __restrict__ hp, float* __restrict__ as_, float* __restrict__ ad_) {
    const int RPB = 8;
    __shared__ float hs[RPB][FIN];
    int j = threadIdx.x;            // output column 0..255
    int base = blockIdx.x * RPB;
    for (int idx = j; idx < RPB * FIN; idx += 256) {
        int r = idx / FIN, k = idx % FIN;
        hs[r][k] = h[(base + r) * FIN + k];
    }
    __syncthreads();
    float acc[RPB];
    #pragma unroll
    for (int r = 0; r < RPB; ++r) acc[r] = 0.f;
    for (int k = 0; k < FIN; ++k) {
        float w = lw[k * HC + j];
        #pragma unroll
        for (int r = 0; r < RPB; ++r) acc[r] += hs[r][k] * w;
    }
    float asv = att_s[j], adv = att_d[j];
    int head = j >> 6;              // wave == head (256 threads)
    #pragma unroll
    for (int r = 0; r < RPB; ++r) {
        hp[(size_t)(base + r) * HC + j] = acc[r];
        float ps = acc[r] * asv;
        float pd = acc[r] * adv;
        #pragma unroll
        for (int o = 32; o >= 1; o >>= 1) {
            ps += __shfl_xor(ps, o, 64);
            pd += __shfl_xor(pd, o, 64);
        }
        if ((j & 63) == 0) {
            as_[(base + r) * NH + head] = ps;
            ad_[(base + r) * NH + head] = pd;
        }
    }
}

// ---------------- softmax denominator via CSR: z[n,h] = sum_j exp(e) ----------------
__global__ void k_z_csr(const int* __restrict__ rowptr, const int* __restrict__ esrc,
                        const float* __restrict__ as_, const float* __restrict__ ad_,
                        float* __restrict__ z) {
    int wave = threadIdx.x >> 6, lane = threadIdx.x & 63;
    int n = blockIdx.x * 4 + wave;
    int start = rowptr[n], end = rowptr[n + 1];
    float4 adv = *(const float4*)&ad_[n * NH];
    float a0 = 0.f, a1 = 0.f, a2 = 0.f, a3 = 0.f;
    for (int j = start + lane; j < end; j += 64) {
        int s = esrc[j];
        float4 asv = *(const float4*)&as_[s * NH];
        float e0 = asv.x + adv.x; e0 = e0 > 0.f ? e0 : e0 * NEG_SLOPE; a0 += __expf(e0);
        float e1 = asv.y + adv.y; e1 = e1 > 0.f ? e1 : e1 * NEG_SLOPE; a1 += __expf(e1);
        float e2 = asv.z + adv.z; e2 = e2 > 0.f ? e2 : e2 * NEG_SLOPE; a2 += __expf(e2);
        float e3 = asv.w + adv.w; e3 = e3 > 0.f ? e3 : e3 * NEG_SLOPE; a3 += __expf(e3);
    }
    #pragma unroll
    for (int o = 32; o >= 1; o >>= 1) {
        a0 += __shfl_xor(a0, o, 64);
        a1 += __shfl_xor(a1, o, 64);
        a2 += __shfl_xor(a2, o, 64);
        a3 += __shfl_xor(a3, o, 64);
    }
    if (lane == 0) {
        z[n * NH + 0] = a0; z[n * NH + 1] = a1;
        z[n * NH + 2] = a2; z[n * NH + 3] = a3;
    }
}

// ---- aggregation via CSR + fused bias/LN/ReLU: one wave per node ----
__global__ void k_agg_ln(const int* __restrict__ rowptr, const int* __restrict__ esrc,
                         const float* __restrict__ hp, const float* __restrict__ as_,
                         const float* __restrict__ ad_, const float* __restrict__ z,
                         const float* __restrict__ bias, const float* __restrict__ g,
                         const float* __restrict__ b, float* __restrict__ outv) {
    int wave = threadIdx.x >> 6, lane = threadIdx.x & 63;
    int n = blockIdx.x * 4 + wave;
    int start = rowptr[n], end = rowptr[n + 1];
    float4 adv = *(const float4*)&ad_[n * NH];
    float4 zv  = *(const float4*)&z[n * NH];
    float iz0 = 1.f / (zv.x + 1e-16f);
    float iz1 = 1.f / (zv.y + 1e-16f);
    float iz2 = 1.f / (zv.z + 1e-16f);
    float iz3 = 1.f / (zv.w + 1e-16f);
    float acc0 = 0.f, acc1 = 0.f, acc2 = 0.f, acc3 = 0.f;
    int s = (start < end) ? esrc[start] : 0;
    for (int j = start; j < end; ++j) {
        int snext = (j + 1 < end) ? esrc[j + 1] : 0;
        float4 asv = *(const float4*)&as_[s * NH];
        float e0 = asv.x + adv.x; e0 = e0 > 0.f ? e0 : e0 * NEG_SLOPE;
        float e1 = asv.y + adv.y; e1 = e1 > 0.f ? e1 : e1 * NEG_SLOPE;
        float e2 = asv.z + adv.z; e2 = e2 > 0.f ? e2 : e2 * NEG_SLOPE;
        float e3 = asv.w + adv.w; e3 = e3 > 0.f ? e3 : e3 * NEG_SLOPE;
        float al0 = __expf(e0) * iz0;
        float al1 = __expf(e1) * iz1;
        float al2 = __expf(e2) * iz2;
        float al3 = __expf(e3) * iz3;
        const float* hrow = hp + (size_t)s * HC;
        acc0 += al0 * hrow[lane];
        acc1 += al1 * hrow[lane + 64];
        acc2 += al2 * hrow[lane + 128];
        acc3 += al3 * hrow[lane + 192];
        s = snext;
    }
    // fused bias + layernorm + relu
    float x0 = acc0 + bias[lane];
    float x1 = acc1 + bias[lane + 64];
    float x2 = acc2 + bias[lane + 128];
    float x3 = acc3 + bias[lane + 192];
    float sum = x0 + x1 + x2 + x3;
    #pragma unroll
    for (int o = 32; o >= 1; o >>= 1) sum += __shfl_xor(sum, o, 64);
    float mu = sum * (1.f / HC);
    float d0 = x0 - mu, d1 = x1 - mu, d2 = x2 - mu, d3 = x3 - mu;
    float vs = d0 * d0 + d1 * d1 + d2 * d2 + d3 * d3;
    #pragma unroll
    for (int o = 32; o >= 1; o >>= 1) vs += __shfl_xor(vs, o, 64);
    float rs = rsqrtf(vs * (1.f / HC) + LN_EPS);
    size_t o = (size_t)n * HC + lane;
    outv[o]       = fmaxf(d0 * rs * g[lane]       + b[lane], 0.f);
    outv[o + 64]  = fmaxf(d1 * rs * g[lane + 64]  + b[lane + 64], 0.f);
    outv[o + 128] = fmaxf(d2 * rs * g[lane + 128] + b[lane + 128], 0.f);
    outv[o + 192] = fmaxf(d3 * rs * g[lane + 192] + b[lane + 192], 0.f);
}

// ---------------- mean pool (column sums) ----------------
__global__ void k_colsum(const float* __restrict__ v, float* __restrict__ gacc) {
    int j = threadIdx.x;
    float s = 0.f;
    for (int n = blockIdx.x; n < NN; n += gridDim.x)
        s += v[(size_t)n * HC + j];
    atomicAdd(&gacc[j], s);
}

// ---------------- final GEMV: out = (g/N) @ w_out + b_out ----------------
__global__ void k_final(const float* __restrict__ gacc, const float* __restrict__ w,
                        const float* __restrict__ b, float* __restrict__ out) {
    int o = threadIdx.x;
    float acc = b[o];
    for (int k = 0; k < HC; ++k)
        acc += (gacc[k] * (1.f / NN)) * w[k * NOUT + o];
    out[o] = acc;
}

extern "C" void kernel_launch(void* const* d_in, const int* in_sizes, int n_in,
                              void* d_out, int out_size, void* d_ws, size_t ws_size,
                              hipStream_t stream) {
    const float* x      = (const float*)d_in[0];
    const int*   eiraw  = (const int*)d_in[1];
    const float* w_in   = (const float*)d_in[2];
    const float* b_in   = (const float*)d_in[3];
    const float* lin0_w = (const float*)d_in[4];
    const float* atts0  = (const float*)d_in[5];
    const float* attd0  = (const float*)d_in[6];
    const float* bias0  = (const float*)d_in[7];
    const float* ln0g   = (const float*)d_in[8];
    const float* ln0b   = (const float*)d_in[9];
    const float* lin1_w = (const float*)d_in[10];
    const float* atts1  = (const float*)d_in[11];
    const float* attd1  = (const float*)d_in[12];
    const float* bias1  = (const float*)d_in[13];
    const float* ln1g   = (const float*)d_in[14];
    const float* ln1b   = (const float*)d_in[15];
    const float* w_out  = (const float*)d_in[16];
    const float* b_out  = (const float*)d_in[17];
    float* out = (float*)d_out;

    char* ws = (char*)d_ws;
    size_t off = 0;
    auto alloc = [&](size_t bytes) {
        void* p = ws + off;
        off = (off + bytes + 255) & ~(size_t)255;
        return p;
    };
    int*   src    = (int*)  alloc((size_t)EP * 4);
    int*   dst    = (int*)  alloc((size_t)EP * 4);
    int*   esrc   = (int*)  alloc((size_t)EP * 4);
    int*   deg    = (int*)  alloc((size_t)NN * 4);
    int*   cursor = (int*)  alloc((size_t)NN * 4);
    int*   rowptr = (int*)  alloc((size_t)(NN + 1) * 4);
    int*   flag   = (int*)  alloc(256);
    float* h0     = (float*)alloc((size_t)NN * HIDD * 4);
    float* hp     = (float*)alloc((size_t)NN * HC * 4);
    float* h1     = (float*)alloc((size_t)NN * HC * 4);
    float* as_    = (float*)alloc((size_t)NN * NH * 4);
    float* ad_    = (float*)alloc((size_t)NN * NH * 4);
    float* z      = (float*)alloc((size_t)NN * NH * 4);
    float* gacc   = (float*)alloc(HC * 4);

    // ---- edge prep + CSR (shared by both layers) ----
    k_detect<<<1, 256, 0, stream>>>(eiraw, flag);
    k_build_edges<<<(EP + 255) / 256, 256, 0, stream>>>(eiraw, flag, src, dst);
    hipMemsetAsync(deg, 0, (size_t)NN * 4, stream);
    k_hist<<<(EP + 255) / 256, 256, 0, stream>>>(dst, deg);
    k_scan<<<1, 1024, 0, stream>>>(deg, rowptr);
    k_copy<<<(NN + 255) / 256, 256, 0, stream>>>(rowptr, cursor, NN);
    k_scatter<<<(EP + 255) / 256, 256, 0, stream>>>(src, dst, cursor, esrc);

    // ---- input projection ----
    k_in_proj<<<NN / 4, 256, 0, stream>>>(x, w_in, b_in, h0);

    // ---- GAT layer 0 ----
    k_lin_att<HIDD><<<NN / 8, 256, 0, stream>>>(h0, lin0_w, atts0, attd0, hp, as_, ad_);
    k_z_csr<<<NN / 4, 256, 0, stream>>>(rowptr, esrc, as_, ad_, z);
    k_agg_ln<<<NN / 4, 256, 0, stream>>>(rowptr, esrc, hp, as_, ad_, z, bias0, ln0g, ln0b, h1);

    // ---- GAT layer 1 ----
    k_lin_att<HC><<<NN / 8, 256, 0, stream>>>(h1, lin1_w, atts1, attd1, hp, as_, ad_);
    k_z_csr<<<NN / 4, 256, 0, stream>>>(rowptr, esrc, as_, ad_, z);
    k_agg_ln<<<NN / 4, 256, 0, stream>>>(rowptr, esrc, hp, as_, ad_, z, bias1, ln1g, ln1b, h1);

    // ---- pool + output ----
    hipMemsetAsync(gacc, 0, HC * 4, stream);
    k_colsum<<<512, 256, 0, stream>>>(h1, gacc);
    k_final<<<1, 256, 0, stream>>>(gacc, w_out, b_out, out);
}

// Round 3
// 543.321 us; speedup vs baseline: 3.7952x; 1.3351x over previous
//
#include <hip/hip_runtime.h>

#define NN 50000
#define EE 800000
#define EP (EE + NN)   // 850000 edges incl. self loops
#define NH 4
#define HC 256
#define NOUT 256
#define NEG_SLOPE 0.2f
#define LN_EPS 1e-5f

typedef unsigned short u16;
typedef __attribute__((ext_vector_type(8))) short bf16x8;
typedef __attribute__((ext_vector_type(4))) float f32x4;

__device__ __forceinline__ u16 f2bf(float f) {
    unsigned int u = __float_as_uint(f);
    u += 0x7fff + ((u >> 16) & 1);           // round-to-nearest-even
    return (u16)(u >> 16);
}
__device__ __forceinline__ float bf2f(u16 s) {
    return __uint_as_float(((unsigned int)s) << 16);
}

// ---------------- edge index handling (int32 vs int64 hedge) ----------------
__global__ void k_detect(const int* __restrict__ raw, int* __restrict__ flag) {
    __shared__ int any;
    if (threadIdx.x == 0) any = 0;
    __syncthreads();
    int found = 0;
    for (int i = threadIdx.x; i < 4096; i += 256)
        if (raw[2 * i + 1] != 0) found = 1;
    if (found) atomicOr(&any, 1);
    __syncthreads();
    if (threadIdx.x == 0) *flag = any;   // 1 => int32 layout, 0 => int64 (low words)
}

__global__ void k_build_edges(const int* __restrict__ raw, const int* __restrict__ flag,
                              int* __restrict__ src, int* __restrict__ dst) {
    int e = blockIdx.x * blockDim.x + threadIdx.x;
    if (e >= EP) return;
    if (e >= EE) { src[e] = e - EE; dst[e] = e - EE; return; }
    if (*flag) { src[e] = raw[e];     dst[e] = raw[EE + e]; }
    else       { src[e] = raw[2 * e]; dst[e] = raw[2 * (EE + e)]; }
}

// ---------------- CSR build ----------------
__global__ void k_hist(const int* __restrict__ dst, int* __restrict__ deg) {
    int e = blockIdx.x * blockDim.x + threadIdx.x;
    if (e < EP) atomicAdd(&deg[dst[e]], 1);
}

__global__ void k_scan(const int* __restrict__ deg, int* __restrict__ rowptr) {
    __shared__ int wsum[16];
    __shared__ int carry_s;
    int lane = threadIdx.x & 63, wid = threadIdx.x >> 6;
    if (threadIdx.x == 0) { carry_s = 0; rowptr[0] = 0; }
    __syncthreads();
    for (int base = 0; base < NN; base += 1024) {
        int i = base + threadIdx.x;
        int x = (i < NN) ? deg[i] : 0;
        #pragma unroll
        for (int o = 1; o < 64; o <<= 1) {
            int t = __shfl_up(x, o, 64);
            if (lane >= o) x += t;
        }
        if (lane == 63) wsum[wid] = x;
        __syncthreads();
        if (wid == 0 && lane < 16) {
            int s = wsum[lane];
            #pragma unroll
            for (int o = 1; o < 16; o <<= 1) {
                int t = __shfl_up(s, o, 64);
                if (lane >= o) s += t;
            }
            wsum[lane] = s;
        }
        __syncthreads();
        int offset = carry_s + (wid > 0 ? wsum[wid - 1] : 0);
        if (i < NN) rowptr[i + 1] = offset + x;
        __syncthreads();
        if (threadIdx.x == 0) carry_s += wsum[15];
        __syncthreads();
    }
}

__global__ void k_copy(const int* __restrict__ a, int* __restrict__ b, int n) {
    int i = blockIdx.x * blockDim.x + threadIdx.x;
    if (i < n) b[i] = a[i];
}

__global__ void k_scatter(const int* __restrict__ src, const int* __restrict__ dst,
                          int* __restrict__ cursor, int* __restrict__ esrc) {
    int e = blockIdx.x * blockDim.x + threadIdx.x;
    if (e >= EP) return;
    int pos = atomicAdd(&cursor[dst[e]], 1);
    esrc[pos] = src[e];
}

// ---------------- casts ----------------
__global__ void k_cast(const float* __restrict__ a, u16* __restrict__ b, int n) {
    int i = blockIdx.x * blockDim.x + threadIdx.x;
    int stride = gridDim.x * blockDim.x;
    for (; i < n; i += stride) b[i] = f2bf(a[i]);
}

// w[K][N] fp32 -> wT[N][K] bf16
__global__ void k_cast_wT(const float* __restrict__ w, u16* __restrict__ wT, int K, int N) {
    int i = blockIdx.x * blockDim.x + threadIdx.x;
    if (i >= K * N) return;
    int k = i / N, j = i - k * N;
    wT[j * K + k] = f2bf(w[i]);
}

// ------- input projection (MFMA): h0 = relu(x @ w_in + b_in), bf16 out -------
// xb [NN][128] bf16, wT [64][128] bf16. Block: 4 waves, each 64 rows x 64 cols.
__global__ void k_proj_mfma(const u16* __restrict__ xb, const u16* __restrict__ wT,
                            const float* __restrict__ bias, u16* __restrict__ h0) {
    int wave = threadIdx.x >> 6, lane = threadIdx.x & 63;
    int lr = lane & 15, lk = lane >> 4;
    int rowbase = (blockIdx.x * 4 + wave) * 64;
    f32x4 acc[4][4];
    #pragma unroll
    for (int mf = 0; mf < 4; ++mf)
        #pragma unroll
        for (int nf = 0; nf < 4; ++nf) acc[mf][nf] = (f32x4)0.f;
    for (int kk = 0; kk < 128; kk += 32) {
        bf16x8 a[4], b[4];
        #pragma unroll
        for (int mf = 0; mf < 4; ++mf) {
            int row = rowbase + mf * 16 + lr;
            a[mf] = (row < NN) ? *(const bf16x8*)&xb[(size_t)row * 128 + kk + lk * 8]
                               : (bf16x8)(short)0;
        }
        #pragma unroll
        for (int nf = 0; nf < 4; ++nf)
            b[nf] = *(const bf16x8*)&wT[(size_t)(nf * 16 + lr) * 128 + kk + lk * 8];
        #pragma unroll
        for (int mf = 0; mf < 4; ++mf)
            #pragma unroll
            for (int nf = 0; nf < 4; ++nf)
                acc[mf][nf] = __builtin_amdgcn_mfma_f32_16x16x32_bf16(a[mf], b[nf], acc[mf][nf], 0, 0, 0);
    }
    #pragma unroll
    for (int mf = 0; mf < 4; ++mf)
        #pragma unroll
        for (int r = 0; r < 4; ++r) {
            int row = rowbase + mf * 16 + lk * 4 + r;
            if (row < NN) {
                #pragma unroll
                for (int nf = 0; nf < 4; ++nf) {
                    int col = nf * 16 + lr;
                    h0[(size_t)row * 64 + col] = f2bf(fmaxf(acc[mf][nf][r] + bias[col], 0.f));
                }
            }
        }
}

// ------- GAT linear (MFMA) + fused attention dots -------
// h [NN][K] bf16, wT [256][K] bf16 -> hp [NN][256] bf16, as_/ad_ [NN][4] fp32.
// Block: 4 waves; wave w = head w = cols [w*64, w*64+64); 64 rows per block.
template<int K>
__global__ void k_lin_att_mfma(const u16* __restrict__ h, const u16* __restrict__ wT,
                               const float* __restrict__ att_s, const float* __restrict__ att_d,
                               u16* __restrict__ hp, float* __restrict__ as_, float* __restrict__ ad_) {
    int wave = threadIdx.x >> 6, lane = threadIdx.x & 63;
    int lr = lane & 15, lk = lane >> 4;
    int rowbase = blockIdx.x * 64;
    f32x4 acc[4][4];
    #pragma unroll
    for (int mf = 0; mf < 4; ++mf)
        #pragma unroll
        for (int nf = 0; nf < 4; ++nf) acc[mf][nf] = (f32x4)0.f;
    for (int kk = 0; kk < K; kk += 32) {
        bf16x8 a[4], b[4];
        #pragma unroll
        for (int mf = 0; mf < 4; ++mf) {
            int row = rowbase + mf * 16 + lr;
            a[mf] = (row < NN) ? *(const bf16x8*)&h[(size_t)row * K + kk + lk * 8]
                               : (bf16x8)(short)0;
        }
        #pragma unroll
        for (int nf = 0; nf < 4; ++nf)
            b[nf] = *(const bf16x8*)&wT[(size_t)(wave * 64 + nf * 16 + lr) * K + kk + lk * 8];
        #pragma unroll
        for (int mf = 0; mf < 4; ++mf)
            #pragma unroll
            for (int nf = 0; nf < 4; ++nf)
                acc[mf][nf] = __builtin_amdgcn_mfma_f32_16x16x32_bf16(a[mf], b[nf], acc[mf][nf], 0, 0, 0);
    }
    float asv[4], adv[4];
    #pragma unroll
    for (int nf = 0; nf < 4; ++nf) {
        int col = wave * 64 + nf * 16 + lr;
        asv[nf] = att_s[col];
        adv[nf] = att_d[col];
    }
    #pragma unroll
    for (int mf = 0; mf < 4; ++mf) {
        float ps[4] = {0.f, 0.f, 0.f, 0.f}, pd[4] = {0.f, 0.f, 0.f, 0.f};
        #pragma unroll
        for (int r = 0; r < 4; ++r) {
            int row = rowbase + mf * 16 + lk * 4 + r;
            #pragma unroll
            for (int nf = 0; nf < 4; ++nf) {
                float v = acc[mf][nf][r];
                ps[r] += v * asv[nf];
                pd[r] += v * adv[nf];
                if (row < NN)
                    hp[(size_t)row * HC + wave * 64 + nf * 16 + lr] = f2bf(v);
            }
        }
        #pragma unroll
        for (int r = 0; r < 4; ++r) {
            float s = ps[r], d = pd[r];
            #pragma unroll
            for (int o = 1; o < 16; o <<= 1) {
                s += __shfl_xor(s, o, 16);
                d += __shfl_xor(d, o, 16);
            }
            int row = rowbase + mf * 16 + lk * 4 + r;
            if (lr == 0 && row < NN) {
                as_[row * NH + wave] = s;
                ad_[row * NH + wave] = d;
            }
        }
    }
}

// ---- fused z + aggregation + bias/LN/ReLU: one wave per node, lane owns 4 cols ----
__global__ void k_agg_ln(const int* __restrict__ rowptr, const int* __restrict__ esrc,
                         const u16* __restrict__ hp, const float* __restrict__ as_,
                         const float* __restrict__ ad_,
                         const float* __restrict__ bias, const float* __restrict__ g,
                         const float* __restrict__ b, u16* __restrict__ outv) {
    int wave = threadIdx.x >> 6, lane = threadIdx.x & 63;
    int n = blockIdx.x * 4 + wave;
    int start = rowptr[n], end = rowptr[n + 1];
    float4 adv4 = *(const float4*)&ad_[n * NH];
    // pass 1: softmax denominators (lane-parallel over edges)
    float z0 = 0.f, z1 = 0.f, z2 = 0.f, z3 = 0.f;
    for (int j = start + lane; j < end; j += 64) {
        int s = esrc[j];
        float4 asv = *(const float4*)&as_[s * NH];
        float e0 = asv.x + adv4.x; e0 = e0 > 0.f ? e0 : e0 * NEG_SLOPE; z0 += __expf(e0);
        float e1 = asv.y + adv4.y; e1 = e1 > 0.f ? e1 : e1 * NEG_SLOPE; z1 += __expf(e1);
        float e2 = asv.z + adv4.z; e2 = e2 > 0.f ? e2 : e2 * NEG_SLOPE; z2 += __expf(e2);
        float e3 = asv.w + adv4.w; e3 = e3 > 0.f ? e3 : e3 * NEG_SLOPE; z3 += __expf(e3);
    }
    #pragma unroll
    for (int o = 32; o >= 1; o >>= 1) {
        z0 += __shfl_xor(z0, o, 64);
        z1 += __shfl_xor(z1, o, 64);
        z2 += __shfl_xor(z2, o, 64);
        z3 += __shfl_xor(z3, o, 64);
    }
    int head = lane >> 4;                 // lane's 4 cols all in this head
    float zh = head == 0 ? z0 : head == 1 ? z1 : head == 2 ? z2 : z3;
    float izh = 1.f / (zh + 1e-16f);
    float advh = ((const float*)&adv4)[head];
    // pass 2: weighted gather, 1-deep software pipeline
    float a0 = 0.f, a1 = 0.f, a2 = 0.f, a3 = 0.f;
    int s = esrc[start];
    ushort4 hv = *(const ushort4*)&hp[(size_t)s * HC + lane * 4];
    float av = as_[s * NH + head];
    for (int j = start; j < end; ++j) {
        int jn = (j + 1 < end) ? j + 1 : j;
        int sn = esrc[jn];
        ushort4 hvn = *(const ushort4*)&hp[(size_t)sn * HC + lane * 4];
        float avn = as_[sn * NH + head];
        float e = av + advh; e = e > 0.f ? e : e * NEG_SLOPE;
        float al = __expf(e) * izh;
        a0 += al * bf2f(hv.x);
        a1 += al * bf2f(hv.y);
        a2 += al * bf2f(hv.z);
        a3 += al * bf2f(hv.w);
        hv = hvn; av = avn;
    }
    // fused bias + layernorm + relu on cols lane*4 .. lane*4+3
    int c = lane * 4;
    float x0 = a0 + bias[c], x1 = a1 + bias[c + 1], x2 = a2 + bias[c + 2], x3 = a3 + bias[c + 3];
    float sum = x0 + x1 + x2 + x3;
    #pragma unroll
    for (int o = 32; o >= 1; o >>= 1) sum += __shfl_xor(sum, o, 64);
    float mu = sum * (1.f / HC);
    float d0 = x0 - mu, d1 = x1 - mu, d2 = x2 - mu, d3 = x3 - mu;
    float vs = d0 * d0 + d1 * d1 + d2 * d2 + d3 * d3;
    #pragma unroll
    for (int o = 32; o >= 1; o >>= 1) vs += __shfl_xor(vs, o, 64);
    float rs = rsqrtf(vs * (1.f / HC) + LN_EPS);
    float y0 = fmaxf(d0 * rs * g[c]     + b[c],     0.f);
    float y1 = fmaxf(d1 * rs * g[c + 1] + b[c + 1], 0.f);
    float y2 = fmaxf(d2 * rs * g[c + 2] + b[c + 2], 0.f);
    float y3 = fmaxf(d3 * rs * g[c + 3] + b[c + 3], 0.f);
    *(ushort4*)&outv[(size_t)n * HC + c] = make_ushort4(f2bf(y0), f2bf(y1), f2bf(y2), f2bf(y3));
}

// ---------------- mean pool (column sums, bf16 in) ----------------
__global__ void k_colsum(const u16* __restrict__ v, float* __restrict__ gacc) {
    int j = threadIdx.x;
    float s = 0.f;
    for (int n = blockIdx.x; n < NN; n += gridDim.x)
        s += bf2f(v[(size_t)n * HC + j]);
    atomicAdd(&gacc[j], s);
}

// ---------------- final GEMV: out = (g/N) @ w_out + b_out ----------------
__global__ void k_final(const float* __restrict__ gacc, const float* __restrict__ w,
                        const float* __restrict__ b, float* __restrict__ out) {
    int o = threadIdx.x;
    float acc = b[o];
    for (int k = 0; k < HC; ++k)
        acc += (gacc[k] * (1.f / NN)) * w[k * NOUT + o];
    out[o] = acc;
}

extern "C" void kernel_launch(void* const* d_in, const int* in_sizes, int n_in,
                              void* d_out, int out_size, void* d_ws, size_t ws_size,
                              hipStream_t stream) {
    const float* x      = (const float*)d_in[0];
    const int*   eiraw  = (const int*)d_in[1];
    const float* w_in   = (const float*)d_in[2];
    const float* b_in   = (const float*)d_in[3];
    const float* lin0_w = (const float*)d_in[4];
    const float* atts0  = (const float*)d_in[5];
    const float* attd0  = (const float*)d_in[6];
    const float* bias0  = (const float*)d_in[7];
    const float* ln0g   = (const float*)d_in[8];
    const float* ln0b   = (const float*)d_in[9];
    const float* lin1_w = (const float*)d_in[10];
    const float* atts1  = (const float*)d_in[11];
    const float* attd1  = (const float*)d_in[12];
    const float* bias1  = (const float*)d_in[13];
    const float* ln1g   = (const float*)d_in[14];
    const float* ln1b   = (const float*)d_in[15];
    const float* w_out  = (const float*)d_in[16];
    const float* b_out  = (const float*)d_in[17];
    float* out = (float*)d_out;

    char* ws = (char*)d_ws;
    size_t off = 0;
    auto alloc = [&](size_t bytes) {
        void* p = ws + off;
        off = (off + bytes + 255) & ~(size_t)255;
        return p;
    };
    int*   src    = (int*)  alloc((size_t)EP * 4);
    int*   dst    = (int*)  alloc((size_t)EP * 4);
    int*   esrc   = (int*)  alloc((size_t)EP * 4);
    int*   deg    = (int*)  alloc((size_t)NN * 4);
    int*   cursor = (int*)  alloc((size_t)NN * 4);
    int*   rowptr = (int*)  alloc((size_t)(NN + 1) * 4);
    int*   flag   = (int*)  alloc(256);
    u16*   xb     = (u16*)  alloc((size_t)NN * 128 * 2);
    u16*   winT   = (u16*)  alloc((size_t)64 * 128 * 2);
    u16*   w0T    = (u16*)  alloc((size_t)256 * 64 * 2);
    u16*   w1T    = (u16*)  alloc((size_t)256 * 256 * 2);
    u16*   h0b    = (u16*)  alloc((size_t)NN * 64 * 2);
    u16*   hpb    = (u16*)  alloc((size_t)NN * HC * 2);
    u16*   h1b    = (u16*)  alloc((size_t)NN * HC * 2);
    float* as_    = (float*)alloc((size_t)NN * NH * 4);
    float* ad_    = (float*)alloc((size_t)NN * NH * 4);
    float* gacc   = (float*)alloc(HC * 4);

    // ---- edge prep + CSR (shared by both layers) ----
    k_detect<<<1, 256, 0, stream>>>(eiraw, flag);
    k_build_edges<<<(EP + 255) / 256, 256, 0, stream>>>(eiraw, flag, src, dst);
    hipMemsetAsync(deg, 0, (size_t)NN * 4, stream);
    k_hist<<<(EP + 255) / 256, 256, 0, stream>>>(dst, deg);
    k_scan<<<1, 1024, 0, stream>>>(deg, rowptr);
    k_copy<<<(NN + 255) / 256, 256, 0, stream>>>(rowptr, cursor, NN);
    k_scatter<<<(EP + 255) / 256, 256, 0, stream>>>(src, dst, cursor, esrc);

    // ---- casts ----
    k_cast<<<2048, 256, 0, stream>>>(x, xb, NN * 128);
    k_cast_wT<<<(128 * 64 + 255) / 256, 256, 0, stream>>>(w_in, winT, 128, 64);
    k_cast_wT<<<(64 * 256 + 255) / 256, 256, 0, stream>>>(lin0_w, w0T, 64, 256);
    k_cast_wT<<<(256 * 256 + 255) / 256, 256, 0, stream>>>(lin1_w, w1T, 256, 256);

    // ---- input projection ----
    k_proj_mfma<<<(NN + 255) / 256, 256, 0, stream>>>(xb, winT, b_in, h0b);

    // ---- GAT layer 0 ----
    k_lin_att_mfma<64><<<(NN + 63) / 64, 256, 0, stream>>>(h0b, w0T, atts0, attd0, hpb, as_, ad_);
    k_agg_ln<<<NN / 4, 256, 0, stream>>>(rowptr, esrc, hpb, as_, ad_, bias0, ln0g, ln0b, h1b);

    // ---- GAT layer 1 ----
    k_lin_att_mfma<256><<<(NN + 63) / 64, 256, 0, stream>>>(h1b, w1T, atts1, attd1, hpb, as_, ad_);
    k_agg_ln<<<NN / 4, 256, 0, stream>>>(rowptr, esrc, hpb, as_, ad_, bias1, ln1g, ln1b, h1b);

    // ---- pool + output ----
    hipMemsetAsync(gacc, 0, HC * 4, stream);
    k_colsum<<<512, 256, 0, stream>>>(h1b, gacc);
    k_final<<<1, 256, 0, stream>>>(gacc, w_out, b_out, out);
}

// Round 4
// 364.260 us; speedup vs baseline: 5.6608x; 1.4916x over previous
//
#include <hip/hip_runtime.h>

#define NN 50000
#define EE 800000
#define EP (EE + NN)   // 850000 edges incl. self loops
#define NH 4
#define HC 256
#define NOUT 256
#define NEG_SLOPE 0.2f
#define LN_EPS 1e-5f
#define NB 49          // ceil(NN/1024)

typedef unsigned short u16;
typedef __attribute__((ext_vector_type(8))) short bf16x8;
typedef __attribute__((ext_vector_type(8))) unsigned short ushort8;
typedef __attribute__((ext_vector_type(4))) float f32x4;

__device__ __forceinline__ u16 f2bf(float f) {
    unsigned int u = __float_as_uint(f);
    u += 0x7fff + ((u >> 16) & 1);           // round-to-nearest-even
    return (u16)(u >> 16);
}
__device__ __forceinline__ float bf2f(u16 s) {
    return __uint_as_float(((unsigned int)s) << 16);
}

// ---------------- edge index handling (int32 vs int64 hedge) ----------------
__global__ void k_detect(const int* __restrict__ raw, int* __restrict__ flag) {
    __shared__ int any;
    if (threadIdx.x == 0) any = 0;
    __syncthreads();
    int found = 0;
    for (int i = threadIdx.x; i < 4096; i += 256)
        if (raw[2 * i + 1] != 0) found = 1;
    if (found) atomicOr(&any, 1);
    __syncthreads();
    if (threadIdx.x == 0) *flag = any;   // 1 => int32 layout, 0 => int64 (low words)
}

// build src/dst with self loops + fused degree histogram
__global__ void k_build_edges(const int* __restrict__ raw, const int* __restrict__ flag,
                              int* __restrict__ src, int* __restrict__ dst,
                              int* __restrict__ deg) {
    int e = blockIdx.x * blockDim.x + threadIdx.x;
    if (e >= EP) return;
    int s, d;
    if (e >= EE) { s = e - EE; d = s; }
    else if (*flag) { s = raw[e];     d = raw[EE + e]; }
    else            { s = raw[2 * e]; d = raw[2 * (EE + e)]; }
    src[e] = s; dst[e] = d;
    atomicAdd(&deg[d], 1);
}

// ---------------- 3-phase scan: deg -> rowptr/cursor ----------------
__global__ void k_scanA(const int* __restrict__ deg, int* __restrict__ tmp,
                        int* __restrict__ bsum) {
    __shared__ int ws[16];
    int lane = threadIdx.x & 63, wid = threadIdx.x >> 6;
    int i = blockIdx.x * 1024 + threadIdx.x;
    int x = (i < NN) ? deg[i] : 0;
    #pragma unroll
    for (int o = 1; o < 64; o <<= 1) {
        int t = __shfl_up(x, o, 64);
        if (lane >= o) x += t;
    }
    if (lane == 63) ws[wid] = x;
    __syncthreads();
    if (wid == 0 && lane < 16) {
        int s = ws[lane];
        #pragma unroll
        for (int o = 1; o < 16; o <<= 1) {
            int t = __shfl_up(s, o, 64);
            if (lane >= o) s += t;
        }
        ws[lane] = s;
    }
    __syncthreads();
    x += (wid > 0) ? ws[wid - 1] : 0;
    if (i < NN) tmp[i] = x;
    if (threadIdx.x == 1023) bsum[blockIdx.x] = x;
}

__global__ void k_scanB(int* __restrict__ bsum, int nb) {
    int lane = threadIdx.x & 63;
    int orig = (lane < nb) ? bsum[lane] : 0;
    int x = orig;
    #pragma unroll
    for (int o = 1; o < 64; o <<= 1) {
        int t = __shfl_up(x, o, 64);
        if (lane >= o) x += t;
    }
    if (lane < nb) bsum[lane] = x - orig;   // exclusive
}

__global__ void k_scanC(const int* __restrict__ tmp, const int* __restrict__ bsum,
                        const int* __restrict__ deg, int* __restrict__ rowptr,
                        int* __restrict__ cursor) {
    int i = blockIdx.x * 1024 + threadIdx.x;
    if (i >= NN) return;
    int fin = tmp[i] + bsum[blockIdx.x];
    rowptr[i + 1] = fin;
    cursor[i] = fin - deg[i];
    if (i == 0) rowptr[0] = 0;
}

__global__ void k_scatter(const int* __restrict__ src, const int* __restrict__ dst,
                          int* __restrict__ cursor, int* __restrict__ esrc) {
    int e = blockIdx.x * blockDim.x + threadIdx.x;
    if (e >= EP) return;
    int pos = atomicAdd(&cursor[dst[e]], 1);
    esrc[pos] = src[e];
}

// ---------------- casts ----------------
__global__ void k_cast(const float* __restrict__ a, u16* __restrict__ b, int n) {
    int i = blockIdx.x * blockDim.x + threadIdx.x;
    int stride = gridDim.x * blockDim.x;
    for (; i < n; i += stride) b[i] = f2bf(a[i]);
}

// w[K][N] fp32 -> wT[N][K] bf16
__global__ void k_cast_wT(const float* __restrict__ w, u16* __restrict__ wT, int K, int N) {
    int i = blockIdx.x * blockDim.x + threadIdx.x;
    if (i >= K * N) return;
    int k = i / N, j = i - k * N;
    wT[j * K + k] = f2bf(w[i]);
}

// ------- input projection (MFMA): h0 = relu(x @ w_in + b_in), bf16 out -------
__global__ void k_proj_mfma(const u16* __restrict__ xb, const u16* __restrict__ wT,
                            const float* __restrict__ bias, u16* __restrict__ h0) {
    int wave = threadIdx.x >> 6, lane = threadIdx.x & 63;
    int lr = lane & 15, lk = lane >> 4;
    int rowbase = (blockIdx.x * 4 + wave) * 64;
    f32x4 acc[4][4];
    #pragma unroll
    for (int mf = 0; mf < 4; ++mf)
        #pragma unroll
        for (int nf = 0; nf < 4; ++nf) acc[mf][nf] = (f32x4)0.f;
    for (int kk = 0; kk < 128; kk += 32) {
        bf16x8 a[4], b[4];
        #pragma unroll
        for (int mf = 0; mf < 4; ++mf) {
            int row = rowbase + mf * 16 + lr;
            a[mf] = (row < NN) ? *(const bf16x8*)&xb[(size_t)row * 128 + kk + lk * 8]
                               : (bf16x8)(short)0;
        }
        #pragma unroll
        for (int nf = 0; nf < 4; ++nf)
            b[nf] = *(const bf16x8*)&wT[(size_t)(nf * 16 + lr) * 128 + kk + lk * 8];
        #pragma unroll
        for (int mf = 0; mf < 4; ++mf)
            #pragma unroll
            for (int nf = 0; nf < 4; ++nf)
                acc[mf][nf] = __builtin_amdgcn_mfma_f32_16x16x32_bf16(a[mf], b[nf], acc[mf][nf], 0, 0, 0);
    }
    #pragma unroll
    for (int mf = 0; mf < 4; ++mf)
        #pragma unroll
        for (int r = 0; r < 4; ++r) {
            int row = rowbase + mf * 16 + lk * 4 + r;
            if (row < NN) {
                #pragma unroll
                for (int nf = 0; nf < 4; ++nf) {
                    int col = nf * 16 + lr;
                    h0[(size_t)row * 64 + col] = f2bf(fmaxf(acc[mf][nf][r] + bias[col], 0.f));
                }
            }
        }
}

// ------- GAT linear (MFMA) + fused attention dots -------
template<int K>
__global__ void k_lin_att_mfma(const u16* __restrict__ h, const u16* __restrict__ wT,
                               const float* __restrict__ att_s, const float* __restrict__ att_d,
                               u16* __restrict__ hp, float* __restrict__ as_, float* __restrict__ ad_) {
    int wave = threadIdx.x >> 6, lane = threadIdx.x & 63;
    int lr = lane & 15, lk = lane >> 4;
    int rowbase = blockIdx.x * 64;
    f32x4 acc[4][4];
    #pragma unroll
    for (int mf = 0; mf < 4; ++mf)
        #pragma unroll
        for (int nf = 0; nf < 4; ++nf) acc[mf][nf] = (f32x4)0.f;
    for (int kk = 0; kk < K; kk += 32) {
        bf16x8 a[4], b[4];
        #pragma unroll
        for (int mf = 0; mf < 4; ++mf) {
            int row = rowbase + mf * 16 + lr;
            a[mf] = (row < NN) ? *(const bf16x8*)&h[(size_t)row * K + kk + lk * 8]
                               : (bf16x8)(short)0;
        }
        #pragma unroll
        for (int nf = 0; nf < 4; ++nf)
            b[nf] = *(const bf16x8*)&wT[(size_t)(wave * 64 + nf * 16 + lr) * K + kk + lk * 8];
        #pragma unroll
        for (int mf = 0; mf < 4; ++mf)
            #pragma unroll
            for (int nf = 0; nf < 4; ++nf)
                acc[mf][nf] = __builtin_amdgcn_mfma_f32_16x16x32_bf16(a[mf], b[nf], acc[mf][nf], 0, 0, 0);
    }
    float asv[4], adv[4];
    #pragma unroll
    for (int nf = 0; nf < 4; ++nf) {
        int col = wave * 64 + nf * 16 + lr;
        asv[nf] = att_s[col];
        adv[nf] = att_d[col];
    }
    #pragma unroll
    for (int mf = 0; mf < 4; ++mf) {
        float ps[4] = {0.f, 0.f, 0.f, 0.f}, pd[4] = {0.f, 0.f, 0.f, 0.f};
        #pragma unroll
        for (int r = 0; r < 4; ++r) {
            int row = rowbase + mf * 16 + lk * 4 + r;
            #pragma unroll
            for (int nf = 0; nf < 4; ++nf) {
                float v = acc[mf][nf][r];
                ps[r] += v * asv[nf];
                pd[r] += v * adv[nf];
                if (row < NN)
                    hp[(size_t)row * HC + wave * 64 + nf * 16 + lr] = f2bf(v);
            }
        }
        #pragma unroll
        for (int r = 0; r < 4; ++r) {
            float s = ps[r], d = pd[r];
            #pragma unroll
            for (int o = 1; o < 16; o <<= 1) {
                s += __shfl_xor(s, o, 16);
                d += __shfl_xor(d, o, 16);
            }
            int row = rowbase + mf * 16 + lk * 4 + r;
            if (lr == 0 && row < NN) {
                as_[row * NH + wave] = s;
                ad_[row * NH + wave] = d;
            }
        }
    }
}

// ---- single-pass fused agg + softmax-norm + bias/LN/ReLU ----
// wave per node; per 64-edge chunk: lanes compute w (LDS-staged), then
// half-wave-per-edge ushort8 gather with 1-ahead prefetch.
#define CHUNK 64
__global__ void k_agg_ln(const int* __restrict__ rowptr, const int* __restrict__ esrc,
                         const u16* __restrict__ hp, const float* __restrict__ as_,
                         const float* __restrict__ ad_,
                         const float* __restrict__ bias, const float* __restrict__ g,
                         const float* __restrict__ b, u16* __restrict__ outv) {
    __shared__ float sw[4][CHUNK][4];
    __shared__ int   ss[4][CHUNK];
    int wave = threadIdx.x >> 6, lane = threadIdx.x & 63;
    int n = blockIdx.x * 4 + wave;
    int start = rowptr[n], end = rowptr[n + 1];
    float4 adv = *(const float4*)&ad_[n * NH];
    int l32 = lane & 31, half = lane >> 5;
    int c = l32 * 8, head = l32 >> 3;
    float acc[8];
    #pragma unroll
    for (int k = 0; k < 8; ++k) acc[k] = 0.f;
    float z0 = 0.f, z1 = 0.f, z2 = 0.f, z3 = 0.f;

    for (int base = start; base < end; base += CHUNK) {
        int m = end - base; if (m > CHUNK) m = CHUNK;
        // phase 1: lane-parallel edge weights into LDS
        if (lane < m) {
            int s = esrc[base + lane];
            float4 asv = *(const float4*)&as_[s * NH];
            float e0 = asv.x + adv.x; e0 = e0 > 0.f ? e0 : e0 * NEG_SLOPE; float w0 = __expf(e0);
            float e1 = asv.y + adv.y; e1 = e1 > 0.f ? e1 : e1 * NEG_SLOPE; float w1 = __expf(e1);
            float e2 = asv.z + adv.z; e2 = e2 > 0.f ? e2 : e2 * NEG_SLOPE; float w2 = __expf(e2);
            float e3 = asv.w + adv.w; e3 = e3 > 0.f ? e3 : e3 * NEG_SLOPE; float w3 = __expf(e3);
            ss[wave][lane] = s;
            *(float4*)&sw[wave][lane][0] = make_float4(w0, w1, w2, w3);
            z0 += w0; z1 += w1; z2 += w2; z3 += w3;
        }
        // phase 2: paired gather (wave-synchronous LDS, no barrier needed)
        int pairs = (m + 1) >> 1;
        int e = half;
        bool v = e < m;
        int s = v ? ss[wave][e] : 0;
        float w = v ? sw[wave][e][head] : 0.f;
        ushort8 hv = *(const ushort8*)&hp[(size_t)s * HC + c];
        for (int it = 0; it < pairs; ++it) {
            int en = e + 2;
            bool vn = en < m;
            int sn = vn ? ss[wave][en] : 0;
            float wn = vn ? sw[wave][en][head] : 0.f;
            ushort8 hvn = *(const ushort8*)&hp[(size_t)sn * HC + c];
            #pragma unroll
            for (int k = 0; k < 8; ++k) acc[k] += w * bf2f(hv[k]);
            e = en; s = sn; w = wn; hv = hvn;
        }
    }
    // combine halves
    #pragma unroll
    for (int k = 0; k < 8; ++k) acc[k] += __shfl_xor(acc[k], 32, 64);
    // softmax denominators
    #pragma unroll
    for (int o = 32; o >= 1; o >>= 1) {
        z0 += __shfl_xor(z0, o, 64);
        z1 += __shfl_xor(z1, o, 64);
        z2 += __shfl_xor(z2, o, 64);
        z3 += __shfl_xor(z3, o, 64);
    }
    float zh = head == 0 ? z0 : head == 1 ? z1 : head == 2 ? z2 : z3;
    float iz = 1.f / (zh + 1e-16f);
    // bias + LN + relu on 8 channels per lane (lanes 0..31 == full row)
    float xv[8], sum = 0.f;
    #pragma unroll
    for (int k = 0; k < 8; ++k) { xv[k] = acc[k] * iz + bias[c + k]; sum += xv[k]; }
    #pragma unroll
    for (int o = 16; o >= 1; o >>= 1) sum += __shfl_xor(sum, o, 64);
    float mu = sum * (1.f / HC);
    float vs = 0.f;
    #pragma unroll
    for (int k = 0; k < 8; ++k) { float d = xv[k] - mu; vs += d * d; }
    #pragma unroll
    for (int o = 16; o >= 1; o >>= 1) vs += __shfl_xor(vs, o, 64);
    float rs = rsqrtf(vs * (1.f / HC) + LN_EPS);
    if (half == 0) {
        ushort8 yv;
        #pragma unroll
        for (int k = 0; k < 8; ++k) {
            float y = fmaxf((xv[k] - mu) * rs * g[c + k] + b[c + k], 0.f);
            yv[k] = f2bf(y);
        }
        *(ushort8*)&outv[(size_t)n * HC + c] = yv;
    }
}

// ---------------- mean pool (column sums, bf16 in) ----------------
__global__ void k_colsum(const u16* __restrict__ v, float* __restrict__ gacc) {
    int j = threadIdx.x;
    float s = 0.f;
    for (int n = blockIdx.x; n < NN; n += gridDim.x)
        s += bf2f(v[(size_t)n * HC + j]);
    atomicAdd(&gacc[j], s);
}

// ---------------- final GEMV: out = (g/N) @ w_out + b_out ----------------
__global__ void k_final(const float* __restrict__ gacc, const float* __restrict__ w,
                        const float* __restrict__ b, float* __restrict__ out) {
    int o = threadIdx.x;
    float acc = b[o];
    for (int k = 0; k < HC; ++k)
        acc += (gacc[k] * (1.f / NN)) * w[k * NOUT + o];
    out[o] = acc;
}

extern "C" void kernel_launch(void* const* d_in, const int* in_sizes, int n_in,
                              void* d_out, int out_size, void* d_ws, size_t ws_size,
                              hipStream_t stream) {
    const float* x      = (const float*)d_in[0];
    const int*   eiraw  = (const int*)d_in[1];
    const float* w_in   = (const float*)d_in[2];
    const float* b_in   = (const float*)d_in[3];
    const float* lin0_w = (const float*)d_in[4];
    const float* atts0  = (const float*)d_in[5];
    const float* attd0  = (const float*)d_in[6];
    const float* bias0  = (const float*)d_in[7];
    const float* ln0g   = (const float*)d_in[8];
    const float* ln0b   = (const float*)d_in[9];
    const float* lin1_w = (const float*)d_in[10];
    const float* atts1  = (const float*)d_in[11];
    const float* attd1  = (const float*)d_in[12];
    const float* bias1  = (const float*)d_in[13];
    const float* ln1g   = (const float*)d_in[14];
    const float* ln1b   = (const float*)d_in[15];
    const float* w_out  = (const float*)d_in[16];
    const float* b_out  = (const float*)d_in[17];
    float* out = (float*)d_out;

    char* ws = (char*)d_ws;
    size_t off = 0;
    auto alloc = [&](size_t bytes) {
        void* p = ws + off;
        off = (off + bytes + 255) & ~(size_t)255;
        return p;
    };
    int*   src    = (int*)  alloc((size_t)EP * 4);
    int*   dst    = (int*)  alloc((size_t)EP * 4);
    int*   esrc   = (int*)  alloc((size_t)EP * 4);
    int*   deg    = (int*)  alloc((size_t)NN * 4);
    int*   cursor = (int*)  alloc((size_t)NN * 4);
    int*   tmp    = (int*)  alloc((size_t)NN * 4);
    int*   bsum   = (int*)  alloc(64 * 4);
    int*   rowptr = (int*)  alloc((size_t)(NN + 1) * 4);
    int*   flag   = (int*)  alloc(256);
    u16*   xb     = (u16*)  alloc((size_t)NN * 128 * 2);
    u16*   winT   = (u16*)  alloc((size_t)64 * 128 * 2);
    u16*   w0T    = (u16*)  alloc((size_t)256 * 64 * 2);
    u16*   w1T    = (u16*)  alloc((size_t)256 * 256 * 2);
    u16*   h0b    = (u16*)  alloc((size_t)NN * 64 * 2);
    u16*   hpb    = (u16*)  alloc((size_t)NN * HC * 2);
    u16*   h1b    = (u16*)  alloc((size_t)NN * HC * 2);
    float* as_    = (float*)alloc((size_t)NN * NH * 4);
    float* ad_    = (float*)alloc((size_t)NN * NH * 4);
    float* gacc   = (float*)alloc(HC * 4);

    // ---- edge prep + CSR (shared by both layers) ----
    hipMemsetAsync(deg, 0, (size_t)NN * 4, stream);
    k_detect<<<1, 256, 0, stream>>>(eiraw, flag);
    k_build_edges<<<(EP + 255) / 256, 256, 0, stream>>>(eiraw, flag, src, dst, deg);
    k_scanA<<<NB, 1024, 0, stream>>>(deg, tmp, bsum);
    k_scanB<<<1, 64, 0, stream>>>(bsum, NB);
    k_scanC<<<NB, 1024, 0, stream>>>(tmp, bsum, deg, rowptr, cursor);
    k_scatter<<<(EP + 255) / 256, 256, 0, stream>>>(src, dst, cursor, esrc);

    // ---- casts ----
    k_cast<<<2048, 256, 0, stream>>>(x, xb, NN * 128);
    k_cast_wT<<<(128 * 64 + 255) / 256, 256, 0, stream>>>(w_in, winT, 128, 64);
    k_cast_wT<<<(64 * 256 + 255) / 256, 256, 0, stream>>>(lin0_w, w0T, 64, 256);
    k_cast_wT<<<(256 * 256 + 255) / 256, 256, 0, stream>>>(lin1_w, w1T, 256, 256);

    // ---- input projection ----
    k_proj_mfma<<<(NN + 255) / 256, 256, 0, stream>>>(xb, winT, b_in, h0b);

    // ---- GAT layer 0 ----
    k_lin_att_mfma<64><<<(NN + 63) / 64, 256, 0, stream>>>(h0b, w0T, atts0, attd0, hpb, as_, ad_);
    k_agg_ln<<<NN / 4, 256, 0, stream>>>(rowptr, esrc, hpb, as_, ad_, bias0, ln0g, ln0b, h1b);

    // ---- GAT layer 1 ----
    k_lin_att_mfma<256><<<(NN + 63) / 64, 256, 0, stream>>>(h1b, w1T, atts1, attd1, hpb, as_, ad_);
    k_agg_ln<<<NN / 4, 256, 0, stream>>>(rowptr, esrc, hpb, as_, ad_, bias1, ln1g, ln1b, h1b);

    // ---- pool + output ----
    hipMemsetAsync(gacc, 0, HC * 4, stream);
    k_colsum<<<512, 256, 0, stream>>>(h1b, gacc);
    k_final<<<1, 256, 0, stream>>>(gacc, w_out, b_out, out);
}